// Round 1
// baseline (172.877 us; speedup 1.0000x reference)
//
#include <hip/hip_runtime.h>

// Problem: ScatterHorizontal — 9 per-offset 1x1 channel linears + bias,
// scatter-added with horizontal shift d = i-4 (zero outside board).
// out[b,o,h,w] = sum_{i: 0<=w-d<9} ( sum_c W[i,o,c]*x_i[b,c,h,w-d] + bias[i,o] )
//
// Round 0: fp32 VALU baseline (correctness-first).
//  - prep kernel: wtT[i][c][o] = W[i][o][c]; biasEff[w][o] = sum of valid bias[i][o]
//  - main kernel: 1 block per b. LDS slab xs[c][162] in w-major padded layout:
//      xs[c][36 + 9*w + h] = x_i[b,c,h,w], pads zero -> shift = flat -9d offset,
//      branchless inner loop, OOB reads hit pre-zeroed pads.

#define CIN   64
#define COUT  64
#define HH    9
#define WW    9
#define NOFF  9
#define HW    81
#define PLANE 162          // padded plane: (w+4) in [0,18) major, h minor
#define SLAB  (CIN * HW)   // 5184 floats per (b, i)

__global__ __launch_bounds__(256) void prep_kernel(
    const float* __restrict__ wts,   // [9][64][64] (i,o,c)
    const float* __restrict__ bias,  // [9][64]
    float* __restrict__ wtT,         // [9][64][64] (i,c,o)
    float* __restrict__ biasEff)     // [9][64]     (w,o)
{
    int tid = blockIdx.x * blockDim.x + threadIdx.x;
    int stride = gridDim.x * blockDim.x;
    for (int e = tid; e < NOFF * CIN * COUT; e += stride) {
        int i = e / (CIN * COUT);
        int r = e - i * (CIN * COUT);
        int c = r / COUT;
        int o = r - c * COUT;
        wtT[e] = wts[(i * COUT + o) * CIN + c];
    }
    if (blockIdx.x == 0) {
        for (int e = threadIdx.x; e < WW * COUT; e += blockDim.x) {
            int w = e / COUT, o = e - w * COUT;
            int lo = (w - 4 > 0) ? (w - 4) : 0;
            int hi = (w + 4 < 8) ? (w + 4) : 8;
            float s = 0.f;
            for (int i = lo; i <= hi; ++i) s += bias[i * COUT + o];
            biasEff[e] = s;
        }
    }
}

__global__ __launch_bounds__(256) void scatter_main_kernel(
    const float* __restrict__ x0, const float* __restrict__ x1,
    const float* __restrict__ x2, const float* __restrict__ x3,
    const float* __restrict__ x4, const float* __restrict__ x5,
    const float* __restrict__ x6, const float* __restrict__ x7,
    const float* __restrict__ x8,
    const float* __restrict__ wtT,      // [i][c][o]
    const float* __restrict__ biasEff,  // [w][o]
    float* __restrict__ out)            // [b][o][h][w]
{
    __shared__ float xs[CIN * PLANE];   // 41472 B

    const int b    = blockIdx.x;
    const int t    = threadIdx.x;
    const int og   = t & 15;    // o-group: 4 consecutive o
    const int slot = t >> 4;    // 16 pixel-run slots
    const int o0   = og * 4;

    // pixel runs over p' = w*9 + h (w-major flat): slot0 gets 6, others 5 -> 81
    const int start = slot * 5 + (slot ? 1 : 0);
    const int cnt   = slot ? 5 : 6;

    // zero whole LDS slab once (pads stay zero across all i)
    for (int e = t; e < CIN * PLANE; e += 256) xs[e] = 0.f;

    // init accumulators with biasEff[w][o0..o0+3]
    float acc[4][6];
#pragma unroll
    for (int j = 0; j < 6; ++j) {
        int p  = start + j;
        int pc = p < 81 ? p : 80;
        int w  = pc / 9;
        const float4 bv = *(const float4*)&biasEff[w * COUT + o0];
        acc[0][j] = bv.x; acc[1][j] = bv.y; acc[2][j] = bv.z; acc[3][j] = bv.w;
    }

#pragma unroll 1
    for (int i = 0; i < NOFF; ++i) {
        const float* xi;
        switch (i) {
            case 0: xi = x0; break; case 1: xi = x1; break;
            case 2: xi = x2; break; case 3: xi = x3; break;
            case 4: xi = x4; break; case 5: xi = x5; break;
            case 6: xi = x6; break; case 7: xi = x7; break;
            default: xi = x8; break;
        }
        const float* src = xi + (size_t)b * SLAB;

        __syncthreads();   // previous iter's reads done before overwrite
        // stage: global (c,h,w) -> xs[c*162 + 36 + 9*w + h]
        for (int e = t; e < SLAB; e += 256) {
            int c = e / HW;
            int r = e - c * HW;
            int h = r / 9;
            int w = r - h * 9;
            xs[c * PLANE + 36 + 9 * w + h] = src[e];
        }
        __syncthreads();

        const int d     = i - 4;
        const int base0 = 36 + start - 9 * d;   // in [0+, ..] always inside plane

#pragma unroll 4
        for (int c = 0; c < CIN; ++c) {
            const float4 wv = *(const float4*)&wtT[(i * CIN + c) * COUT + o0];
            const float* xrow = &xs[c * PLANE + base0];
#pragma unroll
            for (int j = 0; j < 6; ++j) {
                float xv = xrow[j];
                acc[0][j] = fmaf(wv.x, xv, acc[0][j]);
                acc[1][j] = fmaf(wv.y, xv, acc[1][j]);
                acc[2][j] = fmaf(wv.z, xv, acc[2][j]);
                acc[3][j] = fmaf(wv.w, xv, acc[3][j]);
            }
        }
    }

    // store: p' = w*9+h  ->  out[(b*64+o)*81 + h*9 + w]
    float* ob = out + ((size_t)b * COUT + o0) * HW;
    for (int j = 0; j < cnt; ++j) {
        int p = start + j;
        int w = p / 9;
        int h = p - w * 9;
        int oidx = h * 9 + w;
        ob[0 * HW + oidx] = acc[0][j];
        ob[1 * HW + oidx] = acc[1][j];
        ob[2 * HW + oidx] = acc[2][j];
        ob[3 * HW + oidx] = acc[3][j];
    }
}

extern "C" void kernel_launch(void* const* d_in, const int* in_sizes, int n_in,
                              void* d_out, int out_size, void* d_ws, size_t ws_size,
                              hipStream_t stream) {
    const float* x[9];
    for (int i = 0; i < 9; ++i) x[i] = (const float*)d_in[i];
    const float* wts  = (const float*)d_in[9];   // [9][64][64]
    const float* bias = (const float*)d_in[10];  // [9][64]
    float* out = (float*)d_out;

    // workspace layout: wtT (147456 B) | biasEff (2304 B)
    float* wtT     = (float*)d_ws;
    float* biasEff = (float*)((char*)d_ws + NOFF * CIN * COUT * sizeof(float));

    prep_kernel<<<64, 256, 0, stream>>>(wts, bias, wtT, biasEff);
    scatter_main_kernel<<<1024, 256, 0, stream>>>(
        x[0], x[1], x[2], x[3], x[4], x[5], x[6], x[7], x[8],
        wtT, biasEff, out);
}

// Round 2
// 90.053 us; speedup vs baseline: 1.9197x; 1.9197x over previous
//
#include <hip/hip_runtime.h>
#include <hip/hip_bf16.h>

// ScatterHorizontal: out[b,o,h,w'] = sum_i sum_c W[i,o,c]*x_i[b,c,h,w'-(i-4)] + biasEff
// Round 2: bf16 MFMA version.
//  - prep: wfrag[i][kt][ot][lane][8] = bf16 W in exact mfma B-fragment order;
//          biasEff[w][o] = sum of valid bias[i][o]
//  - main: 1 block/batch, 4 waves = 4 o-tiles. X staged to LDS bf16 in w-major
//    padded plane (row = 36 + 9w + h, rows [0,36)+[117,168) zero) so the shift
//    d=i-4 is a flat -9d row offset and OOB reads hit zero pads.
//    D[pix,o]: 6 m-tiles x 2 k-tiles of mfma_f32_16x16x32_bf16, acc init = biasEff.

#define CIN   64
#define COUT  64
#define NOFF  9
#define HW    81
#define SLAB  (CIN * HW)     // 5184 floats per (b,i)
#define ROWS  168            // padded plane rows (max idx 167 = 36+95+36)
#define RST   72             // bf16 per LDS row (64 + 8 pad; 144 B, 16B-aligned)
#define LDSE  (ROWS * RST)   // 12096 bf16 = 24192 B

typedef short bf16x8 __attribute__((ext_vector_type(8)));
typedef float f32x4  __attribute__((ext_vector_type(4)));

static __device__ __forceinline__ unsigned short f2bf(float v) {
    __hip_bfloat16 h = __float2bfloat16(v);
    return *reinterpret_cast<unsigned short*>(&h);
}

// wfrag flat idx = (((i*2 + kt)*4 + ot)*64 + lane)*8 + j
//   value = bf16( W[i][o = 16*ot + (lane&15)][c = 32*kt + 8*(lane>>4) + j] )
__global__ __launch_bounds__(256) void prep_kernel(
    const float* __restrict__ wts,   // [9][64][64] (i,o,c)
    const float* __restrict__ bias,  // [9][64]
    unsigned short* __restrict__ wfrag,
    float* __restrict__ biasEff)     // [9][64] (w,o)
{
    int tid = blockIdx.x * 256 + threadIdx.x;
    int stride = gridDim.x * 256;
    for (int e = tid; e < NOFF * 4096; e += stride) {
        int j  = e & 7;
        int l  = (e >> 3) & 63;
        int ot = (e >> 9) & 3;
        int kt = (e >> 11) & 1;
        int i  = e >> 12;
        int o  = ot * 16 + (l & 15);
        int c  = kt * 32 + (l >> 4) * 8 + j;
        wfrag[e] = f2bf(wts[(i * COUT + o) * CIN + c]);
    }
    if (blockIdx.x == 0) {
        for (int e = threadIdx.x; e < 9 * COUT; e += 256) {
            int w = e / COUT, o = e - w * COUT;
            int lo = (w - 4 > 0) ? (w - 4) : 0;
            int hi = (w + 4 < 8) ? (w + 4) : 8;
            float s = 0.f;
            for (int i2 = lo; i2 <= hi; ++i2) s += bias[i2 * COUT + o];
            biasEff[e] = s;
        }
    }
}

__global__ __launch_bounds__(256) void scatter_mfma_kernel(
    const float* __restrict__ x0, const float* __restrict__ x1,
    const float* __restrict__ x2, const float* __restrict__ x3,
    const float* __restrict__ x4, const float* __restrict__ x5,
    const float* __restrict__ x6, const float* __restrict__ x7,
    const float* __restrict__ x8,
    const unsigned short* __restrict__ wfrag,
    const float* __restrict__ biasEff,
    float* __restrict__ out)
{
    __shared__ unsigned short xs[LDSE];

    const int b    = blockIdx.x;
    const int t    = threadIdx.x;
    const int wave = t >> 6;      // o-tile (0..3)
    const int lane = t & 63;
    const int l15  = lane & 15;
    const int lhi  = lane >> 4;   // 0..3
    const int o0   = wave * 16;

    // staging role: thread = g*81 + p (t < 243); p fixed per thread
    const int g  = t / 81;
    const int p  = t - g * 81;
    const int sh = p / 9, sw = p - sh * 9;
    const int rowoff = (36 + 9 * sw + sh) * RST;

    const float* xp[NOFF] = { x0, x1, x2, x3, x4, x5, x6, x7, x8 };

    // accumulators init = biasEff[w][o] (w from output pixel row p' = 16m+4*lhi+j)
    f32x4 acc[6];
#pragma unroll
    for (int m = 0; m < 6; ++m) {
#pragma unroll
        for (int j = 0; j < 4; ++j) {
            int pp = 16 * m + 4 * lhi + j;
            int w = pp / 9; if (w > 8) w = 8;   // clamp garbage rows (unstored)
            acc[m][j] = biasEff[w * COUT + o0 + l15];
        }
    }

    // zero LDS once (pad rows stay zero; data rows rewritten each i)
    for (int e = t; e < LDSE; e += 256) xs[e] = 0;
    __syncthreads();

#pragma unroll
    for (int i = 0; i < NOFF; ++i) {
        const float* src = xp[i] + (size_t)b * SLAB;

        // stage x_i[b] -> LDS bf16 (coalesced dword reads; b16 writes)
        if (t < 243) {
#pragma unroll 8
            for (int k = 0; k < 22; ++k) {
                int c = g + 3 * k;
                if (c < 64) xs[rowoff + c] = f2bf(src[c * HW + p]);
            }
        }

        // weight B-fragments (global, fragment-ordered, L2-hot; independent of xs)
        bf16x8 bw0 = *(const bf16x8*)&wfrag[(((i * 2 + 0) * 4 + wave) * 64 + lane) * 8];
        bf16x8 bw1 = *(const bf16x8*)&wfrag[(((i * 2 + 1) * 4 + wave) * 64 + lane) * 8];

        __syncthreads();

        const int rowbase = 36 - 9 * (i - 4);   // row for p'=0 at this shift
#pragma unroll
        for (int m = 0; m < 6; ++m) {
            const int r = (rowbase + 16 * m + l15) * RST;
            bf16x8 a0 = *(const bf16x8*)&xs[r + lhi * 8];
            bf16x8 a1 = *(const bf16x8*)&xs[r + 32 + lhi * 8];
            acc[m] = __builtin_amdgcn_mfma_f32_16x16x32_bf16(a0, bw0, acc[m], 0, 0, 0);
            acc[m] = __builtin_amdgcn_mfma_f32_16x16x32_bf16(a1, bw1, acc[m], 0, 0, 0);
        }

        __syncthreads();   // compute done before next stage overwrites
    }

    // store: D row p' = 9w + h (w-major), col o = o0 + l15
    float* ob = out + ((size_t)b * COUT + o0 + l15) * HW;
#pragma unroll
    for (int m = 0; m < 6; ++m) {
#pragma unroll
        for (int j = 0; j < 4; ++j) {
            int pp = 16 * m + 4 * lhi + j;
            if (pp < 81) {
                int w = pp / 9, h = pp - 9 * w;
                ob[h * 9 + w] = acc[m][j];
            }
        }
    }
}

extern "C" void kernel_launch(void* const* d_in, const int* in_sizes, int n_in,
                              void* d_out, int out_size, void* d_ws, size_t ws_size,
                              hipStream_t stream) {
    const float* x[9];
    for (int i = 0; i < 9; ++i) x[i] = (const float*)d_in[i];
    const float* wts  = (const float*)d_in[9];
    const float* bias = (const float*)d_in[10];
    float* out = (float*)d_out;

    unsigned short* wfrag = (unsigned short*)d_ws;                    // 73728 B
    float* biasEff = (float*)((char*)d_ws + NOFF * 4096 * sizeof(unsigned short));

    prep_kernel<<<144, 256, 0, stream>>>(wts, bias, wfrag, biasEff);
    scatter_mfma_kernel<<<1024, 256, 0, stream>>>(
        x[0], x[1], x[2], x[3], x[4], x[5], x[6], x[7], x[8],
        wfrag, biasEff, out);
}

// Round 3
// 50.400 us; speedup vs baseline: 3.4301x; 1.7868x over previous
//
#include <hip/hip_runtime.h>
#include <hip/hip_bf16.h>

// ScatterHorizontal round 3: async f32 staging (global_load_lds dwordx4) +
// double-buffered LDS + counted vmcnt + transpose-at-read (scalar ds_read_b32,
// conflict-free: stride 81 dwords) + bf16 cvt at use + MFMA.
// out[b,o,h,w'] = sum_i [0<=w'-d_i<9]( sum_c W[i,o,c]*x_i[b,c,h,w'-d_i] + bias[i,o] )

#define CIN   64
#define COUT  64
#define NOFF  9
#define HW    81
#define SLAB  5184          // f32 per (b,i) slab
#define BUFE  5376          // padded f32 per LDS buffer (84*64; tail garbage ok)

typedef short bf16x8 __attribute__((ext_vector_type(8)));
typedef float f32x4  __attribute__((ext_vector_type(4)));

static __device__ __forceinline__ short f2bf(float v) {
    __hip_bfloat16 h = __float2bfloat16(v);
    return *reinterpret_cast<short*>(&h);
}

// wfrag flat idx = (((i*2 + kt)*4 + ot)*64 + lane)*8 + j
//   value = bf16( W[i][o = 16*ot + (lane&15)][c = 32*kt + 8*(lane>>4) + j] )
__global__ __launch_bounds__(256) void prep_kernel(
    const float* __restrict__ wts,   // [9][64][64] (i,o,c)
    const float* __restrict__ bias,  // [9][64]
    short* __restrict__ wfrag,
    float* __restrict__ biasEff)     // [9][64] (w,o)
{
    int tid = blockIdx.x * 256 + threadIdx.x;
    int stride = gridDim.x * 256;
    for (int e = tid; e < NOFF * 4096; e += stride) {
        int j  = e & 7;
        int l  = (e >> 3) & 63;
        int ot = (e >> 9) & 3;
        int kt = (e >> 11) & 1;
        int i  = e >> 12;
        int o  = ot * 16 + (l & 15);
        int c  = kt * 32 + (l >> 4) * 8 + j;
        wfrag[e] = f2bf(wts[(i * COUT + o) * CIN + c]);
    }
    if (blockIdx.x == 0) {
        for (int e = threadIdx.x; e < 9 * COUT; e += 256) {
            int w = e / COUT, o = e - w * COUT;
            int lo = (w - 4 > 0) ? (w - 4) : 0;
            int hi = (w + 4 < 8) ? (w + 4) : 8;
            float s = 0.f;
            for (int i2 = lo; i2 <= hi; ++i2) s += bias[i2 * COUT + o];
            biasEff[e] = s;
        }
    }
}

__global__ __launch_bounds__(256) void scatter_mfma2_kernel(
    const float* __restrict__ x0, const float* __restrict__ x1,
    const float* __restrict__ x2, const float* __restrict__ x3,
    const float* __restrict__ x4, const float* __restrict__ x5,
    const float* __restrict__ x6, const float* __restrict__ x7,
    const float* __restrict__ x8,
    const short* __restrict__ wfrag,
    const float* __restrict__ biasEff,
    float* __restrict__ out)
{
    __shared__ float xs[2 * BUFE];   // 43008 B -> 3 blocks/CU

    const int b    = blockIdx.x;
    const int t    = threadIdx.x;
    const int wid  = t >> 6;
    const int lane = t & 63;
    const int l15  = lane & 15;
    const int lhi  = lane >> 4;      // 0..3
    const int mh   = wid >> 1;       // m-half: rows mh*48 + [0,48)
    const int oh   = wid & 1;        // o-half: cols oh*32 + [0,32)

    const float* xp[NOFF] = { x0, x1, x2, x3, x4, x5, x6, x7, x8 };

    // accumulators init = biasEff[w'][o]
    f32x4 acc[3][2];
#pragma unroll
    for (int mt = 0; mt < 3; ++mt) {
#pragma unroll
        for (int of = 0; of < 2; ++of) {
            const int ocol = oh * 32 + of * 16 + l15;
#pragma unroll
            for (int jj = 0; jj < 4; ++jj) {
                int pp = mh * 48 + mt * 16 + lhi * 4 + jj;
                if (pp > 80) pp = 80;                    // garbage rows: any valid idx
                int wb = pp % 9;
                acc[mt][of][jj] = biasEff[wb * COUT + ocol];
            }
        }
    }

    // ---- staging helper (6 uniform wave-instrs, all lanes active) ----
    // k<5: wave-slice (k*4+wid)*256 f32, lane covers +lane*4 (16B).
    // k=5: tail [5120,5184): all waves redundantly read the 16 chunks
    //      (lanes>=16 clamp src via &15; their dest lands in pad [5184,5376)).
#define STAGE(SRC, NB)                                                          \
    {                                                                           \
        const float* _s = (SRC);                                                \
        float* _l = &xs[(NB) * BUFE];                                           \
        _Pragma("unroll")                                                       \
        for (int _k = 0; _k < 5; ++_k) {                                        \
            const int _off = (_k * 4 + wid) * 256;                              \
            __builtin_amdgcn_global_load_lds(_s + _off + lane * 4,              \
                                             &_l[_off], 16, 0, 0);              \
        }                                                                       \
        __builtin_amdgcn_global_load_lds(_s + 5120 + (lane & 15) * 4,           \
                                         &_l[5120], 16, 0, 0);                  \
    }

    // prologue: stage slab 0 into buf 0
    STAGE(xp[0] + (size_t)b * SLAB, 0)

#pragma unroll
    for (int i = 0; i < NOFF; ++i) {
        // B fragments for this offset (normal vector loads; L2-hot)
        bf16x8 bw[2][2];
#pragma unroll
        for (int kt = 0; kt < 2; ++kt)
#pragma unroll
            for (int of = 0; of < 2; ++of) {
                const int ot = oh * 2 + of;
                bw[kt][of] = *(const bf16x8*)&wfrag[(((i * 2 + kt) * 4 + ot) * 64 + lane) * 8];
            }

        // prefetch next slab into other buffer (stays in flight across barrier)
        if (i < NOFF - 1) {
            STAGE(xp[i + 1] + (size_t)b * SLAB, (i + 1) & 1)
        }

        // wait: current slab (+B) landed; 6 prefetch loads still outstanding
        if (i < NOFF - 1) {
            asm volatile("s_waitcnt vmcnt(6)" ::: "memory");
        } else {
            asm volatile("s_waitcnt vmcnt(0)" ::: "memory");
        }
        __builtin_amdgcn_sched_barrier(0);
        __builtin_amdgcn_s_barrier();
        __builtin_amdgcn_sched_barrier(0);

        const float* xb = &xs[(i & 1) * BUFE];
        const int d = i - 4;

#pragma unroll
        for (int mt = 0; mt < 3; ++mt) {
            const int pA = mh * 48 + mt * 16 + l15;   // A-frag row (m = lane&15)
            const int wA = pA % 9;
            const bool valid = (unsigned)(wA - d) < 9u;
            const int q = valid ? (pA - d) : 0;       // input pixel (natural order)

#pragma unroll
            for (int kt = 0; kt < 2; ++kt) {
                const float* ap = xb + kt * 2592 + lhi * 648 + q;
                float f[8];
#pragma unroll
                for (int j = 0; j < 8; ++j) f[j] = ap[81 * j];
#pragma unroll
                for (int j = 0; j < 8; ++j) f[j] = valid ? f[j] : 0.f;
                bf16x8 af;
#pragma unroll
                for (int j = 0; j < 8; ++j) af[j] = f2bf(f[j]);

                acc[mt][0] = __builtin_amdgcn_mfma_f32_16x16x32_bf16(af, bw[kt][0], acc[mt][0], 0, 0, 0);
                acc[mt][1] = __builtin_amdgcn_mfma_f32_16x16x32_bf16(af, bw[kt][1], acc[mt][1], 0, 0, 0);
            }
        }

        __builtin_amdgcn_sched_barrier(0);
        __builtin_amdgcn_s_barrier();
        __builtin_amdgcn_sched_barrier(0);
    }

    // store: D row p' (natural h*9+w), col o
    float* ob = out + (size_t)b * COUT * HW;
#pragma unroll
    for (int mt = 0; mt < 3; ++mt) {
#pragma unroll
        for (int of = 0; of < 2; ++of) {
            const int ocol = oh * 32 + of * 16 + l15;
#pragma unroll
            for (int jj = 0; jj < 4; ++jj) {
                const int pp = mh * 48 + mt * 16 + lhi * 4 + jj;
                if (pp < 81) ob[ocol * HW + pp] = acc[mt][of][jj];
            }
        }
    }
#undef STAGE
}

extern "C" void kernel_launch(void* const* d_in, const int* in_sizes, int n_in,
                              void* d_out, int out_size, void* d_ws, size_t ws_size,
                              hipStream_t stream) {
    const float* x[9];
    for (int i = 0; i < 9; ++i) x[i] = (const float*)d_in[i];
    const float* wts  = (const float*)d_in[9];
    const float* bias = (const float*)d_in[10];
    float* out = (float*)d_out;

    short* wfrag   = (short*)d_ws;                                   // 73728 B
    float* biasEff = (float*)((char*)d_ws + NOFF * 4096 * sizeof(short));

    prep_kernel<<<144, 256, 0, stream>>>(wts, bias, wfrag, biasEff);
    scatter_mfma2_kernel<<<1024, 256, 0, stream>>>(
        x[0], x[1], x[2], x[3], x[4], x[5], x[6], x[7], x[8],
        wfrag, biasEff, out);
}

// Round 4
// 49.166 us; speedup vs baseline: 3.5162x; 1.0251x over previous
//
#include <hip/hip_runtime.h>
#include <hip/hip_bf16.h>

// ScatterHorizontal round 4: single-buffer LDS (21.5 KB -> 4+ resident blocks/CU,
// occupancy 2x) + plain __syncthreads + inter-block overlap hides staging latency.
// Async f32 staging (global_load_lds dwordx4), transpose-at-read (stride-81
// ds_read pairs -> ds_read2_b32), bf16 cvt at use, mfma_f32_16x16x32_bf16.
// out[b,o,h,w'] = sum_i [0<=w'-d_i<9]( sum_c W[i,o,c]*x_i[b,c,h,w'-d_i] + bias[i,o] )

#define CIN   64
#define COUT  64
#define NOFF  9
#define HW    81
#define SLAB  5184          // f32 per (b,i) slab
#define BUFE  5376          // f32 LDS buffer (5184 + pad for redundant tail lanes)

typedef short bf16x8 __attribute__((ext_vector_type(8)));
typedef float f32x4  __attribute__((ext_vector_type(4)));

static __device__ __forceinline__ short f2bf(float v) {
    __hip_bfloat16 h = __float2bfloat16(v);
    return *reinterpret_cast<short*>(&h);
}

// wfrag flat idx = (((i*2 + kt)*4 + ot)*64 + lane)*8 + j
//   value = bf16( W[i][o = 16*ot + (lane&15)][c = 32*kt + 8*(lane>>4) + j] )
__global__ __launch_bounds__(256) void prep_kernel(
    const float* __restrict__ wts,   // [9][64][64] (i,o,c)
    const float* __restrict__ bias,  // [9][64]
    short* __restrict__ wfrag,
    float* __restrict__ biasEff)     // [9][64] (w,o)
{
    int tid = blockIdx.x * 256 + threadIdx.x;
    int stride = gridDim.x * 256;
    for (int e = tid; e < NOFF * 4096; e += stride) {
        int j  = e & 7;
        int l  = (e >> 3) & 63;
        int ot = (e >> 9) & 3;
        int kt = (e >> 11) & 1;
        int i  = e >> 12;
        int o  = ot * 16 + (l & 15);
        int c  = kt * 32 + (l >> 4) * 8 + j;
        wfrag[e] = f2bf(wts[(i * COUT + o) * CIN + c]);
    }
    if (blockIdx.x == 0) {
        for (int e = threadIdx.x; e < 9 * COUT; e += 256) {
            int w = e / COUT, o = e - w * COUT;
            int lo = (w - 4 > 0) ? (w - 4) : 0;
            int hi = (w + 4 < 8) ? (w + 4) : 8;
            float s = 0.f;
            for (int i2 = lo; i2 <= hi; ++i2) s += bias[i2 * COUT + o];
            biasEff[e] = s;
        }
    }
}

__global__ __launch_bounds__(256) void scatter_mfma3_kernel(
    const float* __restrict__ x0, const float* __restrict__ x1,
    const float* __restrict__ x2, const float* __restrict__ x3,
    const float* __restrict__ x4, const float* __restrict__ x5,
    const float* __restrict__ x6, const float* __restrict__ x7,
    const float* __restrict__ x8,
    const short* __restrict__ wfrag,
    const float* __restrict__ biasEff,
    float* __restrict__ out)
{
    __shared__ float xs[BUFE];   // 21504 B -> LDS allows 7 blocks/CU; grid gives 4

    const int b    = blockIdx.x;
    const int t    = threadIdx.x;
    const int wid  = t >> 6;
    const int lane = t & 63;
    const int l15  = lane & 15;
    const int lhi  = lane >> 4;      // 0..3
    const int mh   = wid >> 1;       // m-half: rows mh*48 + [0,48)
    const int oh   = wid & 1;        // o-half: cols oh*32 + [0,32)

    const float* xp[NOFF] = { x0, x1, x2, x3, x4, x5, x6, x7, x8 };

    // accumulators init = biasEff[w'][o]
    f32x4 acc[3][2];
#pragma unroll
    for (int mt = 0; mt < 3; ++mt) {
#pragma unroll
        for (int of = 0; of < 2; ++of) {
            const int ocol = oh * 32 + of * 16 + l15;
#pragma unroll
            for (int jj = 0; jj < 4; ++jj) {
                int pp = mh * 48 + mt * 16 + lhi * 4 + jj;
                if (pp > 80) pp = 80;                    // garbage rows (unstored)
                int wb = pp % 9;
                acc[mt][of][jj] = biasEff[wb * COUT + ocol];
            }
        }
    }

    // staging: 6 wave-uniform global_load_lds dwordx4 instrs per wave.
    // k<5: chunk (k*4+wid)*256 f32, lane covers +lane*4 (16B).
    // tail [5120,5184): all waves issue redundantly; lanes>=16 clamp src via
    // (lane&15) and their dests land in the pad region [5184,5376).
#define STAGE(SRC)                                                              \
    {                                                                           \
        const float* _s = (SRC);                                                \
        _Pragma("unroll")                                                       \
        for (int _k = 0; _k < 5; ++_k) {                                        \
            const int _off = (_k * 4 + wid) * 256;                              \
            __builtin_amdgcn_global_load_lds(_s + _off + lane * 4,              \
                                             &xs[_off], 16, 0, 0);              \
        }                                                                       \
        __builtin_amdgcn_global_load_lds(_s + 5120 + (lane & 15) * 4,           \
                                         &xs[5120], 16, 0, 0);                  \
    }

#pragma unroll
    for (int i = 0; i < NOFF; ++i) {
        STAGE(xp[i] + (size_t)b * SLAB)

        // B fragments for this offset (vector loads; wfrag is L2-resident)
        bf16x8 bw[2][2];
#pragma unroll
        for (int kt = 0; kt < 2; ++kt)
#pragma unroll
            for (int of = 0; of < 2; ++of) {
                const int ot = oh * 2 + of;
                bw[kt][of] = *(const bf16x8*)&wfrag[(((i * 2 + kt) * 4 + ot) * 64 + lane) * 8];
            }

        __syncthreads();   // drains vmcnt(0): slab + B landed

        const int d = i - 4;
#pragma unroll
        for (int mt = 0; mt < 3; ++mt) {
            const int pA = mh * 48 + mt * 16 + l15;   // A-frag row (m = lane&15)
            const int wA = pA % 9;
            const bool valid = (unsigned)(wA - d) < 9u;
            const int q = valid ? (pA - d) : 0;       // input pixel (natural order)

#pragma unroll
            for (int kt = 0; kt < 2; ++kt) {
                const float* ap = xs + kt * 2592 + lhi * 648 + q;
                float f[8];
#pragma unroll
                for (int j = 0; j < 8; ++j) f[j] = ap[81 * j];
#pragma unroll
                for (int j = 0; j < 8; ++j) f[j] = valid ? f[j] : 0.f;
                bf16x8 af;
#pragma unroll
                for (int j = 0; j < 8; ++j) af[j] = f2bf(f[j]);

                acc[mt][0] = __builtin_amdgcn_mfma_f32_16x16x32_bf16(af, bw[kt][0], acc[mt][0], 0, 0, 0);
                acc[mt][1] = __builtin_amdgcn_mfma_f32_16x16x32_bf16(af, bw[kt][1], acc[mt][1], 0, 0, 0);
            }
        }

        __syncthreads();   // all reads done before next STAGE overwrites
    }

    // store: D row p' (natural h*9+w), col o
    float* ob = out + (size_t)b * COUT * HW;
#pragma unroll
    for (int mt = 0; mt < 3; ++mt) {
#pragma unroll
        for (int of = 0; of < 2; ++of) {
            const int ocol = oh * 32 + of * 16 + l15;
#pragma unroll
            for (int jj = 0; jj < 4; ++jj) {
                const int pp = mh * 48 + mt * 16 + lhi * 4 + jj;
                if (pp < 81) ob[ocol * HW + pp] = acc[mt][of][jj];
            }
        }
    }
#undef STAGE
}

extern "C" void kernel_launch(void* const* d_in, const int* in_sizes, int n_in,
                              void* d_out, int out_size, void* d_ws, size_t ws_size,
                              hipStream_t stream) {
    const float* x[9];
    for (int i = 0; i < 9; ++i) x[i] = (const float*)d_in[i];
    const float* wts  = (const float*)d_in[9];
    const float* bias = (const float*)d_in[10];
    float* out = (float*)d_out;

    short* wfrag   = (short*)d_ws;                                   // 73728 B
    float* biasEff = (float*)((char*)d_ws + NOFF * 4096 * sizeof(short));

    prep_kernel<<<144, 256, 0, stream>>>(wts, bias, wfrag, biasEff);
    scatter_mfma3_kernel<<<1024, 256, 0, stream>>>(
        x[0], x[1], x[2], x[3], x[4], x[5], x[6], x[7], x[8],
        wfrag, biasEff, out);
}

// Round 5
// 47.884 us; speedup vs baseline: 3.6103x; 1.0268x over previous
//
#include <hip/hip_runtime.h>
#include <hip/hip_bf16.h>

// ScatterHorizontal round 5: reg-staged bf16 double-buffer pipeline.
//  - stage: global_load_dwordx4 -> regs (issued at iter top), cvt f32->bf16,
//    ds_write_b64 into the OTHER buffer (flat [c][81] bf16 mirror, aligned,
//    conflict-free). No global_load_lds => barrier needs NO vmcnt drain.
//  - one {lgkmcnt(0); s_barrier} per iter (double buffer).
//  - A-frag: 8 ds_read_u16 (stride 81, d16-pairable) + 4 cndmask for the
//    shift boundary (q = p'-d clamped; invalid lanes zeroed).
//  - 12 mfma_f32_16x16x32_bf16 per thread per iter; acc init = biasEff.
// out[b,o,h,w'] = sum_i [0<=w'-d_i<9]( sum_c W[i,o,c]*x_i[b,c,h,w'-d_i] + bias[i,o] )

#define CIN   64
#define COUT  64
#define NOFF  9
#define HW    81
#define SLAB  5184          // f32 per (b,i) slab
#define BUFH  5184          // bf16 per LDS buffer

typedef short bf16x8 __attribute__((ext_vector_type(8)));
typedef float f32x4  __attribute__((ext_vector_type(4)));

static __device__ __forceinline__ unsigned short f2bf(float v) {
    union { __hip_bfloat16 h; unsigned short u; } cv;
    cv.h = __float2bfloat16(v);
    return cv.u;
}

// two u16 LDS loads packed into one dword (lets compiler use ds_read_u16_d16_hi)
static __device__ __forceinline__ int ld2(const unsigned short* p, int i0, int i1) {
    ushort2 v;
    v.x = p[i0];
    v.y = p[i1];
    return (int)v.x | ((int)v.y << 16);
}

// wfrag flat idx = (((i*2 + kt)*4 + ot)*64 + lane)*8 + j
//   value = bf16( W[i][o = 16*ot + (lane&15)][c = 32*kt + 8*(lane>>4) + j] )
__global__ __launch_bounds__(256) void prep_kernel(
    const float* __restrict__ wts,   // [9][64][64] (i,o,c)
    const float* __restrict__ bias,  // [9][64]
    unsigned short* __restrict__ wfrag,
    float* __restrict__ biasEff)     // [9][64] (w,o)
{
    int tid = blockIdx.x * 256 + threadIdx.x;
    int stride = gridDim.x * 256;
    for (int e = tid; e < NOFF * 4096; e += stride) {
        int j  = e & 7;
        int l  = (e >> 3) & 63;
        int ot = (e >> 9) & 3;
        int kt = (e >> 11) & 1;
        int i  = e >> 12;
        int o  = ot * 16 + (l & 15);
        int c  = kt * 32 + (l >> 4) * 8 + j;
        wfrag[e] = f2bf(wts[(i * COUT + o) * CIN + c]);
    }
    if (blockIdx.x == 0) {
        for (int e = threadIdx.x; e < 9 * COUT; e += 256) {
            int w = e / COUT, o = e - w * COUT;
            int lo = (w - 4 > 0) ? (w - 4) : 0;
            int hi = (w + 4 < 8) ? (w + 4) : 8;
            float s = 0.f;
            for (int i2 = lo; i2 <= hi; ++i2) s += bias[i2 * COUT + o];
            biasEff[e] = s;
        }
    }
}

__global__ __launch_bounds__(256, 4) void scatter_mfma4_kernel(
    const float* __restrict__ x0, const float* __restrict__ x1,
    const float* __restrict__ x2, const float* __restrict__ x3,
    const float* __restrict__ x4, const float* __restrict__ x5,
    const float* __restrict__ x6, const float* __restrict__ x7,
    const float* __restrict__ x8,
    const unsigned short* __restrict__ wfrag,
    const float* __restrict__ biasEff,
    float* __restrict__ out)
{
    __shared__ unsigned short xs[2 * BUFH];   // 20736 B

    const int b    = blockIdx.x;
    const int t    = threadIdx.x;
    const int wid  = t >> 6;
    const int lane = t & 63;
    const int l15  = lane & 15;
    const int lhi  = lane >> 4;      // 0..3
    const int mh   = wid >> 1;       // m-half: rows mh*48 + [0,48)
    const int oh   = wid & 1;        // o-half: cols oh*32 + [0,32)

    const float* xp[NOFF] = { x0, x1, x2, x3, x4, x5, x6, x7, x8 };

    // A-row constants (per mt, fixed across i)
    int pAv[3], wAv[3];
#pragma unroll
    for (int mt = 0; mt < 3; ++mt) {
        pAv[mt] = mh * 48 + mt * 16 + l15;
        wAv[mt] = pAv[mt] % 9;
    }

    // accumulators init = biasEff[w'][o]
    f32x4 acc[3][2];
#pragma unroll
    for (int mt = 0; mt < 3; ++mt) {
#pragma unroll
        for (int of = 0; of < 2; ++of) {
            const int ocol = oh * 32 + of * 16 + l15;
#pragma unroll
            for (int jj = 0; jj < 4; ++jj) {
                int pp = mh * 48 + mt * 16 + lhi * 4 + jj;
                if (pp > 80) pp = 80;                    // garbage rows (unstored)
                acc[mt][of][jj] = biasEff[(pp % 9) * COUT + ocol];
            }
        }
    }

    // ---- prologue: stage slab 0 into buf 0 ----
    // flat chunks: thread t owns chunks k = t + 256*m (m<5; m=5 only t<16).
    // global bytes 16k (aligned), LDS bf16 idx 4k (ds_write_b64 aligned).
    {
        const char* src0 = (const char*)(xp[0] + (size_t)b * SLAB) + t * 16;
        float4 s[6];
#pragma unroll
        for (int m = 0; m < 5; ++m) s[m] = *(const float4*)(src0 + m * 4096);
        if (t < 16) s[5] = *(const float4*)(src0 + 20480);
#pragma unroll
        for (int m = 0; m < 5; ++m) {
            ushort4 v = { f2bf(s[m].x), f2bf(s[m].y), f2bf(s[m].z), f2bf(s[m].w) };
            *(ushort4*)&xs[4 * t + 1024 * m] = v;
        }
        if (t < 16) {
            ushort4 v = { f2bf(s[5].x), f2bf(s[5].y), f2bf(s[5].z), f2bf(s[5].w) };
            *(ushort4*)&xs[4 * t + 5120] = v;
        }
        asm volatile("s_waitcnt lgkmcnt(0)" ::: "memory");
        __builtin_amdgcn_s_barrier();
        __builtin_amdgcn_sched_barrier(0);
    }

#pragma unroll
    for (int i = 0; i < NOFF; ++i) {
        const unsigned short* bufR = &xs[(i & 1) * BUFH];
        unsigned short*       bufW = &xs[((i + 1) & 1) * BUFH];

        // 1) B fragments for this offset (L2-hot; issued first so their
        //    auto-vmcnt wait doesn't cover the stage loads)
        bf16x8 bw[2][2];
#pragma unroll
        for (int kt = 0; kt < 2; ++kt)
#pragma unroll
            for (int of = 0; of < 2; ++of) {
                const int ot = oh * 2 + of;
                bw[kt][of] = *(const bf16x8*)&wfrag[(((i * 2 + kt) * 4 + ot) * 64 + lane) * 8];
            }

        // 2) issue stage loads for slab i+1 -> regs (latency hides under MFMA phase)
        float4 sd[6];
        if (i + 1 < NOFF) {
            const char* src = (const char*)(xp[i + 1] + (size_t)b * SLAB) + t * 16;
#pragma unroll
            for (int m = 0; m < 5; ++m) sd[m] = *(const float4*)(src + m * 4096);
            if (t < 16) sd[5] = *(const float4*)(src + 20480);
        }

        // 3) A-frag reads + MFMA
        const int d = i - 4;
#pragma unroll
        for (int mt = 0; mt < 3; ++mt) {
            const bool valid = (unsigned)(wAv[mt] - d) < 9u;
            int q = pAv[mt] - d;
            q = q < 0 ? 0 : (q > 80 ? 80 : q);   // keep in-bounds; invalid zeroed below
            const int qb = lhi * 648 + q;        // + imm offsets walk c

#pragma unroll
            for (int kt = 0; kt < 2; ++kt) {
                const int K = kt * 2592;
                int4 ai;
                ai.x = ld2(bufR, qb + K,       qb + K + 81);
                ai.y = ld2(bufR, qb + K + 162, qb + K + 243);
                ai.z = ld2(bufR, qb + K + 324, qb + K + 405);
                ai.w = ld2(bufR, qb + K + 486, qb + K + 567);
                if (!valid) { ai.x = 0; ai.y = 0; ai.z = 0; ai.w = 0; }
                bf16x8 af = __builtin_bit_cast(bf16x8, ai);

                acc[mt][0] = __builtin_amdgcn_mfma_f32_16x16x32_bf16(af, bw[kt][0], acc[mt][0], 0, 0, 0);
                acc[mt][1] = __builtin_amdgcn_mfma_f32_16x16x32_bf16(af, bw[kt][1], acc[mt][1], 0, 0, 0);
            }
        }

        // 4) cvt + ds_write slab i+1 into other buffer; 5) single barrier
        if (i + 1 < NOFF) {
#pragma unroll
            for (int m = 0; m < 5; ++m) {
                ushort4 v = { f2bf(sd[m].x), f2bf(sd[m].y), f2bf(sd[m].z), f2bf(sd[m].w) };
                *(ushort4*)&bufW[4 * t + 1024 * m] = v;
            }
            if (t < 16) {
                ushort4 v = { f2bf(sd[5].x), f2bf(sd[5].y), f2bf(sd[5].z), f2bf(sd[5].w) };
                *(ushort4*)&bufW[4 * t + 5120] = v;
            }
            asm volatile("s_waitcnt lgkmcnt(0)" ::: "memory");
            __builtin_amdgcn_s_barrier();
            __builtin_amdgcn_sched_barrier(0);
        }
    }

    // store: D row p' (natural h*9+w), col o
    float* ob = out + (size_t)b * COUT * HW;
#pragma unroll
    for (int mt = 0; mt < 3; ++mt) {
#pragma unroll
        for (int of = 0; of < 2; ++of) {
            const int ocol = oh * 32 + of * 16 + l15;
#pragma unroll
            for (int jj = 0; jj < 4; ++jj) {
                const int pp = mh * 48 + mt * 16 + lhi * 4 + jj;
                if (pp < 81) ob[ocol * HW + pp] = acc[mt][of][jj];
            }
        }
    }
}

extern "C" void kernel_launch(void* const* d_in, const int* in_sizes, int n_in,
                              void* d_out, int out_size, void* d_ws, size_t ws_size,
                              hipStream_t stream) {
    const float* x[9];
    for (int i = 0; i < 9; ++i) x[i] = (const float*)d_in[i];
    const float* wts  = (const float*)d_in[9];
    const float* bias = (const float*)d_in[10];
    float* out = (float*)d_out;

    unsigned short* wfrag = (unsigned short*)d_ws;                    // 73728 B
    float* biasEff = (float*)((char*)d_ws + NOFF * 4096 * sizeof(unsigned short));

    prep_kernel<<<144, 256, 0, stream>>>(wts, bias, wfrag, biasEff);
    scatter_mfma4_kernel<<<1024, 256, 0, stream>>>(
        x[0], x[1], x[2], x[3], x[4], x[5], x[6], x[7], x[8],
        wfrag, biasEff, out);
}

// Round 6
// 47.308 us; speedup vs baseline: 3.6543x; 1.0122x over previous
//
#include <hip/hip_runtime.h>
#include <hip/hip_bf16.h>

// ScatterHorizontal round 6: transpose-on-WRITE LDS layout [pixel][c].
//  - stage: thread=(g,p) fixed pixel; per c-quad 4 coalesced dword loads ->
//    pack bf16x4 -> ONE ds_write_b64 at row p (imm-offset walk, no addr VALU).
//  - read: A-frag = 2 x ds_read_b64 per (mt,kt) -> 12 DS reads/thread (was 48),
//    no packing VALU, no per-element cndmask.
//  - boundary: zero row 81 per buffer; q_safe = valid ? pA-d : 81.
//  - double-buffered bf16 LDS (2 x 82 x 136 B = 22.3 KB), 1 barrier/iter,
//    reg-staged issue-early/write-late (R5 structure).
// out[b,o,h,w'] = sum_i [0<=w'-d_i<9]( sum_c W[i,o,c]*x_i[b,c,h,w'-d_i] + bias[i,o] )

#define CIN   64
#define COUT  64
#define NOFF  9
#define HW    81
#define SLAB  5184           // f32 per (b,i) slab
#define RSTB  136            // LDS row stride bytes (64 bf16 = 128 + 8 pad)
#define BUFB  (82 * RSTB)    // 11152 B per buffer (rows 0..80 data, row 81 zero)

typedef short bf16x8 __attribute__((ext_vector_type(8)));
typedef float f32x4  __attribute__((ext_vector_type(4)));

static __device__ __forceinline__ unsigned int f2bf(float v) {
    union { __hip_bfloat16 h; unsigned short u; } cv;
    cv.h = __float2bfloat16(v);
    return (unsigned int)cv.u;
}

// wfrag flat idx = (((i*2 + kt)*4 + ot)*64 + lane)*8 + j
//   value = bf16( W[i][o = 16*ot + (lane&15)][c = 32*kt + 8*(lane>>4) + j] )
__global__ __launch_bounds__(256) void prep_kernel(
    const float* __restrict__ wts,   // [9][64][64] (i,o,c)
    const float* __restrict__ bias,  // [9][64]
    unsigned short* __restrict__ wfrag,
    float* __restrict__ biasEff)     // [9][64] (w,o)
{
    int tid = blockIdx.x * 256 + threadIdx.x;
    int stride = gridDim.x * 256;
    for (int e = tid; e < NOFF * 4096; e += stride) {
        int j  = e & 7;
        int l  = (e >> 3) & 63;
        int ot = (e >> 9) & 3;
        int kt = (e >> 11) & 1;
        int i  = e >> 12;
        int o  = ot * 16 + (l & 15);
        int c  = kt * 32 + (l >> 4) * 8 + j;
        wfrag[e] = (unsigned short)f2bf(wts[(i * COUT + o) * CIN + c]);
    }
    if (blockIdx.x == 0) {
        for (int e = threadIdx.x; e < 9 * COUT; e += 256) {
            int w = e / COUT, o = e - w * COUT;
            int lo = (w - 4 > 0) ? (w - 4) : 0;
            int hi = (w + 4 < 8) ? (w + 4) : 8;
            float s = 0.f;
            for (int i2 = lo; i2 <= hi; ++i2) s += bias[i2 * COUT + o];
            biasEff[e] = s;
        }
    }
}

__global__ __launch_bounds__(256, 4) void scatter_mfma5_kernel(
    const float* __restrict__ x0, const float* __restrict__ x1,
    const float* __restrict__ x2, const float* __restrict__ x3,
    const float* __restrict__ x4, const float* __restrict__ x5,
    const float* __restrict__ x6, const float* __restrict__ x7,
    const float* __restrict__ x8,
    const unsigned short* __restrict__ wfrag,
    const float* __restrict__ biasEff,
    float* __restrict__ out)
{
    __shared__ __align__(16) unsigned char xs[2 * BUFB];   // 22304 B

    const int b    = blockIdx.x;
    const int t    = threadIdx.x;
    const int wid  = t >> 6;
    const int lane = t & 63;
    const int l15  = lane & 15;
    const int lhi  = lane >> 4;      // 0..3
    const int mh   = wid >> 1;       // m-half: rows mh*48 + [0,48)
    const int oh   = wid & 1;        // o-half: cols oh*32 + [0,32)

    // staging role: thread = (g, p); g=3 (t>=243) inactive
    const int g   = t / 81;
    const int p   = t - g * 81;
    const bool stg = (g < 3);
    const int wbase = p * RSTB + 8 * g;   // LDS byte base for this thread's writes

    const float* xp[NOFF] = { x0, x1, x2, x3, x4, x5, x6, x7, x8 };

    // A-row constants (i-invariant)
    int pAv[3], wAv[3];
#pragma unroll
    for (int mt = 0; mt < 3; ++mt) {
        pAv[mt] = mh * 48 + mt * 16 + l15;
        wAv[mt] = pAv[mt] % 9;
    }

    // accumulators init = biasEff[w'][o]
    f32x4 acc[3][2];
#pragma unroll
    for (int mt = 0; mt < 3; ++mt) {
#pragma unroll
        for (int of = 0; of < 2; ++of) {
            const int ocol = oh * 32 + of * 16 + l15;
#pragma unroll
            for (int jj = 0; jj < 4; ++jj) {
                int pp = mh * 48 + mt * 16 + lhi * 4 + jj;
                if (pp > 80) pp = 80;                    // garbage rows (unstored)
                acc[mt][of][jj] = biasEff[(pp % 9) * COUT + ocol];
            }
        }
    }

    // zero row 81 of both buffers (68 dwords total)
    if (t < 68) {
        int idx = (t < 34) ? (81 * RSTB + 4 * t)
                           : (BUFB + 81 * RSTB + 4 * (t - 34));
        *(unsigned int*)&xs[idx] = 0u;
    }

    // ---- prologue: stage slab 0 -> buf 0 (load+cvt+write directly) ----
    if (stg) {
        const float* sp = xp[0] + (size_t)b * SLAB + g * 324 + p;
        unsigned char* wb = &xs[wbase];
#pragma unroll
        for (int k = 0; k < 5; ++k) {
            float f0 = sp[0], f1 = sp[81], f2 = sp[162], f3 = sp[243];
            uint2 v;
            v.x = f2bf(f0) | (f2bf(f1) << 16);
            v.y = f2bf(f2) | (f2bf(f3) << 16);
            *(uint2*)(wb + 24 * k) = v;
            sp += 972;
        }
        if (g == 0) {   // 16th quad (q=15)
            float f0 = sp[0], f1 = sp[81], f2 = sp[162], f3 = sp[243];
            uint2 v;
            v.x = f2bf(f0) | (f2bf(f1) << 16);
            v.y = f2bf(f2) | (f2bf(f3) << 16);
            *(uint2*)(wb + 120) = v;
        }
    }
    asm volatile("s_waitcnt lgkmcnt(0)" ::: "memory");
    __builtin_amdgcn_s_barrier();
    __builtin_amdgcn_sched_barrier(0);

#pragma unroll
    for (int i = 0; i < NOFF; ++i) {
        const unsigned char* bufR = &xs[(i & 1) * BUFB];

        // 1) B fragments for this offset (vector loads; wfrag L2-hot)
        bf16x8 bw[2][2];
#pragma unroll
        for (int kt = 0; kt < 2; ++kt)
#pragma unroll
            for (int of = 0; of < 2; ++of) {
                const int ot = oh * 2 + of;
                bw[kt][of] = *(const bf16x8*)&wfrag[(((i * 2 + kt) * 4 + ot) * 64 + lane) * 8];
            }

        // 2) issue stage loads for slab i+1 (latency hides under DS+MFMA phase)
        float sf[6][4];
        if (stg && i + 1 < NOFF) {
            const float* sp = xp[i + 1] + (size_t)b * SLAB + g * 324 + p;
#pragma unroll
            for (int k = 0; k < 5; ++k) {
                sf[k][0] = sp[0]; sf[k][1] = sp[81];
                sf[k][2] = sp[162]; sf[k][3] = sp[243];
                sp += 972;
            }
            if (g == 0) {
                sf[5][0] = sp[0]; sf[5][1] = sp[81];
                sf[5][2] = sp[162]; sf[5][3] = sp[243];
            }
        }

        // 3) A-frag reads (12 x ds_read_b64) + 12 MFMA
        const int d = i - 4;
#pragma unroll
        for (int mt = 0; mt < 3; ++mt) {
            const bool valid = (unsigned)(wAv[mt] - d) < 9u;
            const int q = valid ? (pAv[mt] - d) : 81;     // row 81 = zeros
            const unsigned char* rp = bufR + q * RSTB + lhi * 16;

#pragma unroll
            for (int kt = 0; kt < 2; ++kt) {
                int2 lo = *(const int2*)(rp + kt * 64);
                int2 hi = *(const int2*)(rp + kt * 64 + 8);
                int4 ai = { lo.x, lo.y, hi.x, hi.y };
                bf16x8 af = __builtin_bit_cast(bf16x8, ai);

                acc[mt][0] = __builtin_amdgcn_mfma_f32_16x16x32_bf16(af, bw[kt][0], acc[mt][0], 0, 0, 0);
                acc[mt][1] = __builtin_amdgcn_mfma_f32_16x16x32_bf16(af, bw[kt][1], acc[mt][1], 0, 0, 0);
            }
        }

        // 4) cvt + ds_write slab i+1 into the other buffer; 5) barrier
        if (i + 1 < NOFF) {
            if (stg) {
                unsigned char* wb = &xs[((i + 1) & 1) * BUFB + wbase];
#pragma unroll
                for (int k = 0; k < 5; ++k) {
                    uint2 v;
                    v.x = f2bf(sf[k][0]) | (f2bf(sf[k][1]) << 16);
                    v.y = f2bf(sf[k][2]) | (f2bf(sf[k][3]) << 16);
                    *(uint2*)(wb + 24 * k) = v;
                }
                if (g == 0) {
                    uint2 v;
                    v.x = f2bf(sf[5][0]) | (f2bf(sf[5][1]) << 16);
                    v.y = f2bf(sf[5][2]) | (f2bf(sf[5][3]) << 16);
                    *(uint2*)(wb + 120) = v;
                }
            }
            asm volatile("s_waitcnt lgkmcnt(0)" ::: "memory");
            __builtin_amdgcn_s_barrier();
            __builtin_amdgcn_sched_barrier(0);
        }
    }

    // store: D row p' (natural h*9+w), col o
    float* ob = out + (size_t)b * COUT * HW;
#pragma unroll
    for (int mt = 0; mt < 3; ++mt) {
#pragma unroll
        for (int of = 0; of < 2; ++of) {
            const int ocol = oh * 32 + of * 16 + l15;
#pragma unroll
            for (int jj = 0; jj < 4; ++jj) {
                const int pp = mh * 48 + mt * 16 + lhi * 4 + jj;
                if (pp < 81) ob[ocol * HW + pp] = acc[mt][of][jj];
            }
        }
    }
}

extern "C" void kernel_launch(void* const* d_in, const int* in_sizes, int n_in,
                              void* d_out, int out_size, void* d_ws, size_t ws_size,
                              hipStream_t stream) {
    const float* x[9];
    for (int i = 0; i < 9; ++i) x[i] = (const float*)d_in[i];
    const float* wts  = (const float*)d_in[9];
    const float* bias = (const float*)d_in[10];
    float* out = (float*)d_out;

    unsigned short* wfrag = (unsigned short*)d_ws;                    // 73728 B
    float* biasEff = (float*)((char*)d_ws + NOFF * 4096 * sizeof(unsigned short));

    prep_kernel<<<144, 256, 0, stream>>>(wts, bias, wfrag, biasEff);
    scatter_mfma5_kernel<<<1024, 256, 0, stream>>>(
        x[0], x[1], x[2], x[3], x[4], x[5], x[6], x[7], x[8],
        wfrag, biasEff, out);
}